// Round 8
// baseline (542.482 us; speedup 1.0000x reference)
//
#include <hip/hip_runtime.h>
#include <math.h>

typedef float f32x4 __attribute__((ext_vector_type(4)));
typedef __attribute__((ext_vector_type(8))) _Float16 f16x8;

#define DD 256
#define DH 128

// ---------------------------------------------------------------------------
// K0: W1 (256x128 fp32) -> f16 MFMA B-fragment order.
// w1f[((kt*8+nt)*64+l)*8+j] = f16(W1[kt*32+(l>>4)*8+j][nt*16+(l&15)])
// ---------------------------------------------------------------------------
__global__ void ap_prep(const float* __restrict__ W1, _Float16* __restrict__ w1f) {
  int t = blockIdx.x * blockDim.x + threadIdx.x;  // 0..4095
  if (t >= 64 * 64) return;
  int l = t & 63;
  int tile = t >> 6;  // kt*8 + nt
  int kt = tile >> 3, nt = tile & 7;
  int kbase = kt * 32 + (l >> 4) * 8;
  int col = nt * 16 + (l & 15);
#pragma unroll
  for (int j = 0; j < 8; ++j) {
    w1f[t * 8 + j] = (_Float16)W1[(kbase + j) * DH + col];
  }
}

// ---------------------------------------------------------------------------
// K1: segment boundaries (batch sorted). start[b] = first i with batch[i]>=b
// ---------------------------------------------------------------------------
__global__ void ap_bounds(const int* __restrict__ batch, int* __restrict__ start,
                          int nrows, int bseg) {
  int i = blockIdx.x * blockDim.x + threadIdx.x;
  if (i >= nrows) return;
  int c = batch[i];
  int p = (i == 0) ? -1 : batch[i - 1];
  for (int b = p + 1; b <= c; ++b) start[b] = i;
  if (i == nrows - 1) {
    for (int b = c + 1; b <= bseg; ++b) start[b] = nrows;
  }
}

// ---------------------------------------------------------------------------
// K2: fused, block per segment, single x read, ZERO barriers in main loop.
// Each of the 8 waves owns a strided row-stream (wv*16 + 128k) with its own
// online softmax (per-wave max; shift cancels except the 1e-8 term, ~1e-13
// rel). Pooling accumulates row-major in registers (lane = row); the 16-lane
// transpose-sum happens ONCE per segment, not per tile. Wave partials
// (m_w, sw_w, pooled_w) merged after one barrier with exp(m_w - m_f)
// factors. Deterministic: fixed-order reductions, no fp atomics.
// ---------------------------------------------------------------------------
__global__ __launch_bounds__(512)
void ap_fused(const float* __restrict__ x, const _Float16* __restrict__ w1f,
              const float* __restrict__ b1, const float* __restrict__ W2,
              const float* __restrict__ b2, const int* __restrict__ start,
              float* __restrict__ out, int nrows) {
  __shared__ __align__(16) _Float16 sB[64 * 64 * 8];  // 64 KB B fragments
  __shared__ __align__(16) float pooled[8][256];      // per-wave pooled result
  __shared__ float raws[8][16];                       // wave-private raw slots
  __shared__ float mArr[8], swArr[8];

  const int tid = threadIdx.x;
  const int wv = tid >> 6;
  const int l = tid & 63;
  const int l15 = l & 15, lhi = l >> 4;
  const int b = blockIdx.x;
  const int s = start[b], e = start[b + 1];

  // stage B fragments: 4096 x 16B chunks
  {
    const f32x4* src = (const f32x4*)w1f;
    f32x4* dst = (f32x4*)sB;
#pragma unroll
    for (int it = 0; it < 8; ++it) dst[it * 512 + tid] = src[it * 512 + tid];
  }
  __syncthreads();

  float b1f[8], w2f[8];
#pragma unroll
  for (int nt = 0; nt < 8; ++nt) {
    b1f[nt] = b1[nt * 16 + l15];
    w2f[nt] = W2[nt * 16 + l15];
  }
  const float bb = *b2;

  f32x4 accp[16];
#pragma unroll
  for (int j = 0; j < 16; ++j) accp[j] = f32x4{0.f, 0.f, 0.f, 0.f};
  float m = -__builtin_inff();
  float swv = 0.f;

  // main loop: wave-independent, no block barriers
  for (int t0 = s + wv * 16; t0 < e; t0 += 128) {
    const int rowv = t0 + l15;
    const int rowc = (rowv < e) ? rowv : (e - 1);
    const float* xr = x + (size_t)rowc * DD + lhi * 8;
    f32x4 xv[16];
#pragma unroll
    for (int kt = 0; kt < 8; ++kt) {
      xv[2 * kt] = *(const f32x4*)(xr + kt * 32);
      xv[2 * kt + 1] = *(const f32x4*)(xr + kt * 32 + 4);
    }

    // MLP: split-f16 MFMA (hi+lo products), B from LDS
    f32x4 acc[8];
#pragma unroll
    for (int nt = 0; nt < 8; ++nt) acc[nt] = f32x4{0.f, 0.f, 0.f, 0.f};
#pragma unroll
    for (int kt = 0; kt < 8; ++kt) {
      f16x8 ah, al;
#pragma unroll
      for (int j = 0; j < 8; ++j) {
        const float f = (j < 4) ? xv[2 * kt][j] : xv[2 * kt + 1][j - 4];
        const _Float16 h = (_Float16)f;
        ah[j] = h;
        al[j] = (_Float16)(f - (float)h);
      }
      const f16x8* bh = (const f16x8*)sB + (size_t)kt * 512;
#pragma unroll
      for (int nt = 0; nt < 8; ++nt) {
        const f16x8 Bh = bh[nt * 64 + l];
        acc[nt] = __builtin_amdgcn_mfma_f32_16x16x32_f16(ah, Bh, acc[nt], 0, 0, 0);
        acc[nt] = __builtin_amdgcn_mfma_f32_16x16x32_f16(al, Bh, acc[nt], 0, 0, 0);
      }
    }

    // epilogue: relu+b1, dot W2, reduce over 16 col-lanes
    float pr[4];
#pragma unroll
    for (int r = 0; r < 4; ++r) pr[r] = 0.f;
#pragma unroll
    for (int nt = 0; nt < 8; ++nt) {
#pragma unroll
      for (int r = 0; r < 4; ++r)
        pr[r] += fmaxf(acc[nt][r] + b1f[nt], 0.f) * w2f[nt];
    }
#pragma unroll
    for (int mm = 1; mm < 16; mm <<= 1) {
#pragma unroll
      for (int r = 0; r < 4; ++r) pr[r] += __shfl_xor(pr[r], mm, 64);
    }
    // distribute raw to lane=row via wave-private LDS slot (no barrier:
    // within-wave write->read, compiler inserts lgkmcnt)
    if (l15 == 0) {
#pragma unroll
      for (int r = 0; r < 4; ++r) {
        raws[wv][lhi * 4 + r] =
            (t0 + lhi * 4 + r < e) ? (pr[r] + bb) : -__builtin_inff();
      }
    }
    const float myraw = raws[wv][l15];

    // per-wave online softmax update
    float tv = myraw;
#pragma unroll
    for (int mm = 1; mm < 16; mm <<= 1) tv = fmaxf(tv, __shfl_xor(tv, mm, 64));
    const float nm = fmaxf(m, tv);         // tile's row t0 is valid -> finite
    const float factor = expf(m - nm);     // first tile: exp(-inf) = 0
    m = nm;
    const float wrow = expf(myraw - m);    // invalid rows -> 0
    swv = swv * factor + wrow;
#pragma unroll
    for (int j = 0; j < 16; ++j) accp[j] = accp[j] * factor + wrow * xv[j];
  }

  // wave-final: transpose-sum accp over the 16 row-lanes (once per segment)
#pragma unroll
  for (int mm = 1; mm < 16; mm <<= 1) {
#pragma unroll
    for (int j = 0; j < 16; ++j) {
      f32x4 o;
      o[0] = __shfl_xor(accp[j][0], mm, 64);
      o[1] = __shfl_xor(accp[j][1], mm, 64);
      o[2] = __shfl_xor(accp[j][2], mm, 64);
      o[3] = __shfl_xor(accp[j][3], mm, 64);
      accp[j] += o;
    }
  }
  float sww = swv;
#pragma unroll
  for (int mm = 1; mm < 16; mm <<= 1) sww += __shfl_xor(sww, mm, 64);

  // write wave partials (always, so idle-wave slots are zeroed, not poison)
  if (l15 == 0) {
    f32x4* pw = (f32x4*)pooled[wv];
#pragma unroll
    for (int j = 0; j < 16; ++j) {
      const int c = (j >> 1) * 8 + lhi * 2 + (j & 1);
      pw[c] = accp[j];
    }
  }
  if (l == 0) { mArr[wv] = m; swArr[wv] = sww; }
  __syncthreads();

  // merge 8 wave partials (fixed order), scale, write out
  if (tid < 64) {
    float m_f = -__builtin_inff();
#pragma unroll
    for (int q = 0; q < 8; ++q) m_f = fmaxf(m_f, mArr[q]);
    float fac[8];
    float sum_w = 0.f;
#pragma unroll
    for (int q = 0; q < 8; ++q) {
      const float mq = mArr[q];
      fac[q] = (mq == -__builtin_inff()) ? 0.f : expf(mq - m_f);
      sum_w += swArr[q] * fac[q];
    }
    const int cnt = e - s;
    const float cntf = (float)(cnt > 0 ? cnt : 1);
    const float scale = 1.0f / (((sum_w / cntf) * (float)nrows + 1e-8f) * cntf);
    f32x4 r = f32x4{0.f, 0.f, 0.f, 0.f};
#pragma unroll
    for (int q = 0; q < 8; ++q) r += ((f32x4*)pooled[q])[tid] * fac[q];
    r *= scale;
    *(f32x4*)(out + (size_t)b * DD + tid * 4) = r;
  }
}

extern "C" void kernel_launch(void* const* d_in, const int* in_sizes, int n_in,
                              void* d_out, int out_size, void* d_ws, size_t ws_size,
                              hipStream_t stream) {
  const float* x     = (const float*)d_in[0];
  const int*   batch = (const int*)d_in[1];
  const float* W1    = (const float*)d_in[2];
  const float* b1    = (const float*)d_in[3];
  const float* W2    = (const float*)d_in[4];
  const float* b2    = (const float*)d_in[5];
  float* out = (float*)d_out;

  const int nrows = in_sizes[1];
  const int bseg = out_size / DD;

  // workspace layout (16B-aligned)
  _Float16* w1f = (_Float16*)d_ws;                  // 64 KB
  int* start = (int*)(w1f + 64 * 64 * 8);           // bseg+1

  ap_prep<<<16, 256, 0, stream>>>(W1, w1f);
  ap_bounds<<<(nrows + 255) / 256, 256, 0, stream>>>(batch, start, nrows, bseg);
  ap_fused<<<bseg, 512, 0, stream>>>(x, w1f, b1, W2, b2, start, out, nrows);
}

// Round 9
// 421.270 us; speedup vs baseline: 1.2877x; 1.2877x over previous
//
#include <hip/hip_runtime.h>
#include <math.h>

typedef float f32x4 __attribute__((ext_vector_type(4)));
typedef __attribute__((ext_vector_type(8))) _Float16 f16x8;

#define DD 256
#define DH 128

__device__ __forceinline__ f32x4 shflx4(f32x4 v, int mask) {
  f32x4 r;
  r[0] = __shfl_xor(v[0], mask, 64);
  r[1] = __shfl_xor(v[1], mask, 64);
  r[2] = __shfl_xor(v[2], mask, 64);
  r[3] = __shfl_xor(v[3], mask, 64);
  return r;
}

// ---------------------------------------------------------------------------
// K0: W1 (256x128 fp32) -> f16 MFMA B-fragment order.
// w1f[((kt*8+nt)*64+l)*8+j] = f16(W1[kt*32+(l>>4)*8+j][nt*16+(l&15)])
// ---------------------------------------------------------------------------
__global__ void ap_prep(const float* __restrict__ W1, _Float16* __restrict__ w1f) {
  int t = blockIdx.x * blockDim.x + threadIdx.x;  // 0..4095
  if (t >= 64 * 64) return;
  int l = t & 63;
  int tile = t >> 6;  // kt*8 + nt
  int kt = tile >> 3, nt = tile & 7;
  int kbase = kt * 32 + (l >> 4) * 8;
  int col = nt * 16 + (l & 15);
#pragma unroll
  for (int j = 0; j < 8; ++j) {
    w1f[t * 8 + j] = (_Float16)W1[(kbase + j) * DH + col];
  }
}

// ---------------------------------------------------------------------------
// K1: segment boundaries (batch sorted). start[b] = first i with batch[i]>=b
// ---------------------------------------------------------------------------
__global__ void ap_bounds(const int* __restrict__ batch, int* __restrict__ start,
                          int nrows, int bseg) {
  int i = blockIdx.x * blockDim.x + threadIdx.x;
  if (i >= nrows) return;
  int c = batch[i];
  int p = (i == 0) ? -1 : batch[i - 1];
  for (int b = p + 1; b <= c; ++b) start[b] = i;
  if (i == nrows - 1) {
    for (int b = c + 1; b <= bseg; ++b) start[b] = nrows;
  }
}

// ---------------------------------------------------------------------------
// K2: fused, block per segment, single x read, no barriers in the main loop,
// and NO per-lane accp[16] (round-8's spill): each tile ends with a 4-step
// recursive-halving exchange over the 16 row-lanes, leaving ONE f32x4 per
// lane (its column chunk, summed over the tile's 16 rows). Online-softmax
// accumulator is then a single f32x4. All register arrays statically
// indexed. Deterministic: fixed-order reductions, no fp atomics.
// ---------------------------------------------------------------------------
__global__ __launch_bounds__(512, 2)
void ap_fused(const float* __restrict__ x, const _Float16* __restrict__ w1f,
              const float* __restrict__ b1, const float* __restrict__ W2,
              const float* __restrict__ b2, const int* __restrict__ start,
              float* __restrict__ out, int nrows) {
  __shared__ __align__(16) _Float16 sB[64 * 64 * 8];  // 64 KB B fragments
  __shared__ __align__(16) float pooled[8][256];      // per-wave final chunks
  __shared__ float raws[8][16];                       // wave-private raw
  __shared__ float b1s[DH], w2s[DH];
  __shared__ float mArr[8], swArr[8];

  const int tid = threadIdx.x;
  const int wv = tid >> 6;
  const int l = tid & 63;
  const int l15 = l & 15, lhi = l >> 4;
  const int b = blockIdx.x;
  const int s = start[b], e = start[b + 1];

  // stage B fragments (4096 x 16B) + b1/W2
  {
    const f32x4* src = (const f32x4*)w1f;
    f32x4* dst = (f32x4*)sB;
#pragma unroll
    for (int it = 0; it < 8; ++it) dst[it * 512 + tid] = src[it * 512 + tid];
  }
  if (tid < DH) { b1s[tid] = b1[tid]; w2s[tid] = W2[tid]; }
  __syncthreads();

  const float bb = *b2;
  f32x4 accp = {0.f, 0.f, 0.f, 0.f};  // this lane's column chunk
  float m = -__builtin_inff();
  float swv = 0.f;

  // main loop: wave-independent, no block barriers
  for (int t0 = s + wv * 16; t0 < e; t0 += 128) {
    const int rowv = t0 + l15;
    const int rowc = (rowv < e) ? rowv : (e - 1);
    const float* xr = x + (size_t)rowc * DD + lhi * 8;
    f32x4 xv[16];
#pragma unroll
    for (int kt = 0; kt < 8; ++kt) {
      xv[2 * kt] = *(const f32x4*)(xr + kt * 32);
      xv[2 * kt + 1] = *(const f32x4*)(xr + kt * 32 + 4);
    }

    // MLP: split-f16 MFMA (hi+lo), B from LDS
    f32x4 acc[8];
#pragma unroll
    for (int nt = 0; nt < 8; ++nt) acc[nt] = f32x4{0.f, 0.f, 0.f, 0.f};
#pragma unroll
    for (int kt = 0; kt < 8; ++kt) {
      f16x8 ah, al;
#pragma unroll
      for (int j = 0; j < 8; ++j) {
        const float f = (j < 4) ? xv[2 * kt][j] : xv[2 * kt + 1][j - 4];
        const _Float16 h = (_Float16)f;
        ah[j] = h;
        al[j] = (_Float16)(f - (float)h);
      }
      const f16x8* bh = (const f16x8*)sB + (size_t)kt * 512;
#pragma unroll
      for (int nt = 0; nt < 8; ++nt) {
        const f16x8 Bh = bh[nt * 64 + l];
        acc[nt] = __builtin_amdgcn_mfma_f32_16x16x32_f16(ah, Bh, acc[nt], 0, 0, 0);
        acc[nt] = __builtin_amdgcn_mfma_f32_16x16x32_f16(al, Bh, acc[nt], 0, 0, 0);
      }
    }

    // epilogue: relu+b1, dot W2 (from LDS), reduce over 16 col-lanes
    float pr[4];
#pragma unroll
    for (int r = 0; r < 4; ++r) pr[r] = 0.f;
#pragma unroll
    for (int nt = 0; nt < 8; ++nt) {
      const float b1f = b1s[nt * 16 + l15];
      const float w2f = w2s[nt * 16 + l15];
#pragma unroll
      for (int r = 0; r < 4; ++r)
        pr[r] += fmaxf(acc[nt][r] + b1f, 0.f) * w2f;
    }
#pragma unroll
    for (int mm = 1; mm < 16; mm <<= 1) {
#pragma unroll
      for (int r = 0; r < 4; ++r) pr[r] += __shfl_xor(pr[r], mm, 64);
    }
    // distribute raw to lane=row via wave-private LDS slot (in-wave order)
    if (l15 == 0) {
#pragma unroll
      for (int r = 0; r < 4; ++r) {
        raws[wv][lhi * 4 + r] =
            (t0 + lhi * 4 + r < e) ? (pr[r] + bb) : -__builtin_inff();
      }
    }
    const float myraw = raws[wv][l15];

    // per-wave online softmax update
    float tv = myraw;
#pragma unroll
    for (int mm = 1; mm < 16; mm <<= 1) tv = fmaxf(tv, __shfl_xor(tv, mm, 64));
    const float nm = fmaxf(m, tv);         // row t0 valid -> finite
    const float factor = expf(m - nm);     // first tile: exp(-inf) = 0
    m = nm;
    const float wrow = expf(myraw - m);    // invalid rows -> 0
    swv = swv * factor + wrow;

    // scale rows by their weight
#pragma unroll
    for (int j = 0; j < 16; ++j) xv[j] *= wrow;

    // 4-step recursive-halving exchange over the 16 row-lanes:
    // lane keeps chunks whose bit_k == bit_k(l15); after 4 steps lane holds
    // chunk c = l15 (cols lhi*8 + (l15>>1)*32 + (l15&1)*4) summed over rows.
    f32x4 y[8];
    {
      const int bsel = l15 & 1;
#pragma unroll
      for (int j = 0; j < 8; ++j) {
        const f32x4 ta = shflx4(xv[2 * j], 1);
        const f32x4 tb = shflx4(xv[2 * j + 1], 1);
        y[j] = (bsel ? xv[2 * j + 1] : xv[2 * j]) + (bsel ? tb : ta);
      }
    }
    f32x4 z[4];
    {
      const int bsel = (l15 >> 1) & 1;
#pragma unroll
      for (int j = 0; j < 4; ++j) {
        const f32x4 ta = shflx4(y[2 * j], 2);
        const f32x4 tb = shflx4(y[2 * j + 1], 2);
        z[j] = (bsel ? y[2 * j + 1] : y[2 * j]) + (bsel ? tb : ta);
      }
    }
    f32x4 u[2];
    {
      const int bsel = (l15 >> 2) & 1;
#pragma unroll
      for (int j = 0; j < 2; ++j) {
        const f32x4 ta = shflx4(z[2 * j], 4);
        const f32x4 tb = shflx4(z[2 * j + 1], 4);
        u[j] = (bsel ? z[2 * j + 1] : z[2 * j]) + (bsel ? tb : ta);
      }
    }
    f32x4 tile;
    {
      const int bsel = (l15 >> 3) & 1;
      const f32x4 ta = shflx4(u[0], 8);
      const f32x4 tb = shflx4(u[1], 8);
      tile = (bsel ? u[1] : u[0]) + (bsel ? tb : ta);
    }
    accp = accp * factor + tile;
  }

  // wave-final: sum_w over the 16 row-lanes (per lhi group, identical copies)
  float sww = swv;
#pragma unroll
  for (int mm = 1; mm < 16; mm <<= 1) sww += __shfl_xor(sww, mm, 64);

  // write wave partials (always: idle waves write zeros, not poison)
  {
    const int chunk = lhi * 2 + (l15 >> 1) * 8 + (l15 & 1);
    *(f32x4*)&pooled[wv][chunk * 4] = accp;
  }
  if (l == 0) { mArr[wv] = m; swArr[wv] = sww; }
  __syncthreads();

  // merge 8 wave partials (fixed order), scale, write out
  if (tid < 64) {
    float m_f = -__builtin_inff();
#pragma unroll
    for (int q = 0; q < 8; ++q) m_f = fmaxf(m_f, mArr[q]);
    float fac[8];
    float sum_w = 0.f;
#pragma unroll
    for (int q = 0; q < 8; ++q) {
      const float mq = mArr[q];
      fac[q] = (mq == -__builtin_inff()) ? 0.f : expf(mq - m_f);
      sum_w += swArr[q] * fac[q];
    }
    const int cnt = e - s;
    const float cntf = (float)(cnt > 0 ? cnt : 1);
    const float scale = 1.0f / (((sum_w / cntf) * (float)nrows + 1e-8f) * cntf);
    f32x4 r = f32x4{0.f, 0.f, 0.f, 0.f};
#pragma unroll
    for (int q = 0; q < 8; ++q) r += ((f32x4*)pooled[q])[tid] * fac[q];
    r *= scale;
    *(f32x4*)(out + (size_t)b * DD + tid * 4) = r;
  }
}

extern "C" void kernel_launch(void* const* d_in, const int* in_sizes, int n_in,
                              void* d_out, int out_size, void* d_ws, size_t ws_size,
                              hipStream_t stream) {
  const float* x     = (const float*)d_in[0];
  const int*   batch = (const int*)d_in[1];
  const float* W1    = (const float*)d_in[2];
  const float* b1    = (const float*)d_in[3];
  const float* W2    = (const float*)d_in[4];
  const float* b2    = (const float*)d_in[5];
  float* out = (float*)d_out;

  const int nrows = in_sizes[1];
  const int bseg = out_size / DD;

  // workspace layout (16B-aligned)
  _Float16* w1f = (_Float16*)d_ws;                  // 64 KB
  int* start = (int*)(w1f + 64 * 64 * 8);           // bseg+1

  ap_prep<<<16, 256, 0, stream>>>(W1, w1f);
  ap_bounds<<<(nrows + 255) / 256, 256, 0, stream>>>(batch, start, nrows, bseg);
  ap_fused<<<bseg, 512, 0, stream>>>(x, w1f, b1, W2, b2, start, out, nrows);
}

// Round 10
// 336.247 us; speedup vs baseline: 1.6133x; 1.2529x over previous
//
#include <hip/hip_runtime.h>
#include <math.h>

typedef float f32x4 __attribute__((ext_vector_type(4)));
typedef __attribute__((ext_vector_type(8))) _Float16 f16x8;

#define DD 256
#define DH 128
#define NSPLIT 4

// ---------------------------------------------------------------------------
// K0: W1 (256x128 fp32) -> f16 MFMA B-fragment order.
// w1f[((kt*8+nt)*64+l)*8+j] = f16(W1[kt*32+(l>>4)*8+j][nt*16+(l&15)])
// ---------------------------------------------------------------------------
__global__ void ap_prep(const float* __restrict__ W1, _Float16* __restrict__ w1f) {
  int t = blockIdx.x * blockDim.x + threadIdx.x;  // 0..4095
  if (t >= 64 * 64) return;
  int l = t & 63;
  int tile = t >> 6;  // kt*8 + nt
  int kt = tile >> 3, nt = tile & 7;
  int kbase = kt * 32 + (l >> 4) * 8;
  int col = nt * 16 + (l & 15);
#pragma unroll
  for (int j = 0; j < 8; ++j) {
    w1f[t * 8 + j] = (_Float16)W1[(kbase + j) * DH + col];
  }
}

// ---------------------------------------------------------------------------
// K1: segment boundaries (batch sorted). start[b] = first i with batch[i]>=b
// ---------------------------------------------------------------------------
__global__ void ap_bounds(const int* __restrict__ batch, int* __restrict__ start,
                          int nrows, int bseg) {
  int i = blockIdx.x * blockDim.x + threadIdx.x;
  if (i >= nrows) return;
  int c = batch[i];
  int p = (i == 0) ? -1 : batch[i - 1];
  for (int b = p + 1; b <= c; ++b) start[b] = i;
  if (i == nrows - 1) {
    for (int b = c + 1; b <= bseg; ++b) start[b] = nrows;
  }
}

// ---------------------------------------------------------------------------
// K2: round-7 fused tile pipeline, but each segment is split into NSPLIT
// contiguous pieces (block = (segment, piece)); piece ~ one 128-row tile.
// Block emits UNSCALED partials (pooledPart[256], mPart, swPart); ap_final
// merges. Per-piece online max; the shift cancels except in the 1e-8 term
// (~1e-13 rel). Deterministic: fixed-order reductions, no fp atomics.
// ---------------------------------------------------------------------------
__global__ __launch_bounds__(512)
void ap_fused(const float* __restrict__ x, const _Float16* __restrict__ w1f,
              const float* __restrict__ b1, const float* __restrict__ W2,
              const float* __restrict__ b2, const int* __restrict__ start,
              float* __restrict__ pooledPart, float* __restrict__ mPart,
              float* __restrict__ swPart, int nrows) {
  __shared__ __align__(16) _Float16 sB[64 * 64 * 8];  // 64 KB B fragments
  __shared__ float rawp[128];                         // raw for tile rows
  __shared__ __align__(16) float pooled[8][256];      // per-wave pooled acc
  __shared__ float swarr[8];

  const int tid = threadIdx.x;
  const int wv = tid >> 6;
  const int l = tid & 63;
  const int l15 = l & 15, lhi = l >> 4;
  const int bi = blockIdx.x;
  const int b = bi >> 2;           // segment
  const int q = bi & (NSPLIT - 1); // piece
  const int s0 = start[b], e0 = start[b + 1];
  const int cnt = e0 - s0;
  const int L = (cnt + NSPLIT - 1) >> 2;
  const int s = s0 + q * L;
  int pe = s + L;
  if (pe > e0) pe = e0;
  const int e = pe;

  // stage B fragments: 4096 x 16B chunks
  {
    const f32x4* src = (const f32x4*)w1f;
    f32x4* dst = (f32x4*)sB;
#pragma unroll
    for (int it = 0; it < 8; ++it) dst[it * 512 + tid] = src[it * 512 + tid];
  }
  ((f32x4*)pooled)[tid] = f32x4{0.f, 0.f, 0.f, 0.f};  // 512 chunks = 8x256 f32
  __syncthreads();

  float b1f[8], w2f[8];
#pragma unroll
  for (int nt = 0; nt < 8; ++nt) {
    b1f[nt] = b1[nt * 16 + l15];
    w2f[nt] = W2[nt * 16 + l15];
  }
  const float bb = *b2;

  float m = -__builtin_inff();
  float swv = 0.f;

  for (int t0 = s; t0 < e; t0 += 128) {
    // ---- load this wave's 16 rows into registers ----
    const int row = t0 + wv * 16 + l15;
    const long long rowc = (row < e) ? row : (long long)(e - 1);
    const float* xr = x + rowc * DD + lhi * 8;
    f32x4 xv[16];
#pragma unroll
    for (int kt = 0; kt < 8; ++kt) {
      xv[2 * kt] = *(const f32x4*)(xr + kt * 32);
      xv[2 * kt + 1] = *(const f32x4*)(xr + kt * 32 + 4);
    }

    // ---- MLP: split-f16 MFMA over all 8 nt (B from LDS) ----
    f32x4 acc[8];
#pragma unroll
    for (int nt = 0; nt < 8; ++nt) acc[nt] = f32x4{0.f, 0.f, 0.f, 0.f};
#pragma unroll
    for (int kt = 0; kt < 8; ++kt) {
      f16x8 ah, al;
#pragma unroll
      for (int j = 0; j < 8; ++j) {
        const float f = (j < 4) ? xv[2 * kt][j] : xv[2 * kt + 1][j - 4];
        const _Float16 h = (_Float16)f;
        ah[j] = h;
        al[j] = (_Float16)(f - (float)h);
      }
      const f16x8* bh = (const f16x8*)sB + (size_t)kt * 512;
#pragma unroll
      for (int nt = 0; nt < 8; ++nt) {
        const f16x8 Bh = bh[nt * 64 + l];
        acc[nt] = __builtin_amdgcn_mfma_f32_16x16x32_f16(ah, Bh, acc[nt], 0, 0, 0);
        acc[nt] = __builtin_amdgcn_mfma_f32_16x16x32_f16(al, Bh, acc[nt], 0, 0, 0);
      }
    }

    // ---- epilogue: relu+b1, dot W2, reduce over 16 col-lanes -> rawp ----
    float pr[4];
#pragma unroll
    for (int r = 0; r < 4; ++r) pr[r] = 0.f;
#pragma unroll
    for (int nt = 0; nt < 8; ++nt) {
#pragma unroll
      for (int r = 0; r < 4; ++r)
        pr[r] += fmaxf(acc[nt][r] + b1f[nt], 0.f) * w2f[nt];
    }
#pragma unroll
    for (int mm = 1; mm < 16; mm <<= 1) {
#pragma unroll
      for (int r = 0; r < 4; ++r) pr[r] += __shfl_xor(pr[r], mm, 64);
    }
    if (l15 == 0) {
      const int wr0 = t0 + wv * 16 + lhi * 4;
#pragma unroll
      for (int r = 0; r < 4; ++r) {
        rawp[wv * 16 + lhi * 4 + r] =
            (wr0 + r < e) ? (pr[r] + bb) : -__builtin_inff();
      }
    }
    __syncthreads();

    // ---- online-softmax update (block-uniform; identical per thread) ----
    float tv = fmaxf(rawp[l], rawp[64 + l]);
#pragma unroll
    for (int mm = 1; mm < 64; mm <<= 1) tv = fmaxf(tv, __shfl_xor(tv, mm, 64));
    const float nm = fmaxf(m, tv);          // row t0 valid -> finite
    const float factor = expf(m - nm);      // first tile: exp(-inf)=0
    m = nm;

    // w for this lane's pooling row (== its x-register row, l15)
    const float wrow = expf(rawp[wv * 16 + l15] - m);  // invalid row -> 0
    float ws_ = wrow;
#pragma unroll
    for (int mm = 1; mm < 16; mm <<= 1) ws_ += __shfl_xor(ws_, mm, 64);
    swv = swv * factor + ws_;

    // ---- pooling: xv *= w, butterfly-sum over the 16 row-lanes ----
#pragma unroll
    for (int j = 0; j < 16; ++j) xv[j] *= wrow;
#pragma unroll
    for (int mm = 1; mm < 16; mm <<= 1) {
#pragma unroll
      for (int j = 0; j < 16; ++j) {
        f32x4 o;
        o[0] = __shfl_xor(xv[j][0], mm, 64);
        o[1] = __shfl_xor(xv[j][1], mm, 64);
        o[2] = __shfl_xor(xv[j][2], mm, 64);
        o[3] = __shfl_xor(xv[j][3], mm, 64);
        xv[j] += o;
      }
    }
    if (l15 == 0) {
      f32x4* pw = (f32x4*)pooled[wv];
#pragma unroll
      for (int j = 0; j < 16; ++j) {
        const int c = lhi * 2 + (j >> 1) * 8 + (j & 1);
        pw[c] = pw[c] * factor + xv[j];
      }
    }
    __syncthreads();  // rawp consumed; next tile may overwrite
  }

  // ---- write piece partials (unscaled) ----
  if (l == 0) swarr[wv] = swv;
  __syncthreads();
  if (tid < 64) {
    float sum_w = 0.f;
#pragma unroll
    for (int p = 0; p < 8; ++p) sum_w += swarr[p];
    f32x4 v = (((f32x4*)pooled[0])[tid] + ((f32x4*)pooled[1])[tid]) +
              (((f32x4*)pooled[2])[tid] + ((f32x4*)pooled[3])[tid]);
    f32x4 w = (((f32x4*)pooled[4])[tid] + ((f32x4*)pooled[5])[tid]) +
              (((f32x4*)pooled[6])[tid] + ((f32x4*)pooled[7])[tid]);
    *(f32x4*)(pooledPart + (size_t)bi * DD + tid * 4) = v + w;
    if (tid == 0) { mPart[bi] = m; swPart[bi] = sum_w; }
  }
}

// ---------------------------------------------------------------------------
// K3: merge the NSPLIT piece partials per segment (fixed order), scale, write.
// ---------------------------------------------------------------------------
__global__ __launch_bounds__(64)
void ap_final(const float* __restrict__ pooledPart, const float* __restrict__ mPart,
              const float* __restrict__ swPart, const int* __restrict__ start,
              float* __restrict__ out, int nrows) {
  const int b = blockIdx.x;
  const int tid = threadIdx.x;
  const float NI = -__builtin_inff();
  float mq[NSPLIT];
#pragma unroll
  for (int qv = 0; qv < NSPLIT; ++qv) mq[qv] = mPart[b * NSPLIT + qv];
  float m_f = NI;
#pragma unroll
  for (int qv = 0; qv < NSPLIT; ++qv) m_f = fmaxf(m_f, mq[qv]);
  float fac[NSPLIT];
  float sum_w = 0.f;
#pragma unroll
  for (int qv = 0; qv < NSPLIT; ++qv) {
    fac[qv] = (mq[qv] == NI) ? 0.f : expf(mq[qv] - m_f);
    sum_w += swPart[b * NSPLIT + qv] * fac[qv];
  }
  const int cnt = start[b + 1] - start[b];
  const float cntf = (float)(cnt > 0 ? cnt : 1);
  const float scale = 1.0f / (((sum_w / cntf) * (float)nrows + 1e-8f) * cntf);
  f32x4 r = f32x4{0.f, 0.f, 0.f, 0.f};
#pragma unroll
  for (int qv = 0; qv < NSPLIT; ++qv) {
    r += ((const f32x4*)(pooledPart + (size_t)(b * NSPLIT + qv) * DD))[tid] * fac[qv];
  }
  r *= scale;
  *(f32x4*)(out + (size_t)b * DD + tid * 4) = r;
}

extern "C" void kernel_launch(void* const* d_in, const int* in_sizes, int n_in,
                              void* d_out, int out_size, void* d_ws, size_t ws_size,
                              hipStream_t stream) {
  const float* x     = (const float*)d_in[0];
  const int*   batch = (const int*)d_in[1];
  const float* W1    = (const float*)d_in[2];
  const float* b1    = (const float*)d_in[3];
  const float* W2    = (const float*)d_in[4];
  const float* b2    = (const float*)d_in[5];
  float* out = (float*)d_out;

  const int nrows = in_sizes[1];
  const int bseg = out_size / DD;

  // workspace layout (16B-aligned)
  float* pooledPart = (float*)d_ws;                        // bseg*4*256 f32 (4MB)
  float* mPart  = pooledPart + (size_t)bseg * NSPLIT * DD; // bseg*4
  float* swPart = mPart + bseg * NSPLIT;                   // bseg*4
  _Float16* w1f = (_Float16*)(swPart + bseg * NSPLIT);     // 64 KB
  int* start = (int*)(w1f + 64 * 64 * 8);                  // bseg+1

  ap_prep<<<16, 256, 0, stream>>>(W1, w1f);
  ap_bounds<<<(nrows + 255) / 256, 256, 0, stream>>>(batch, start, nrows, bseg);
  ap_fused<<<bseg * NSPLIT, 512, 0, stream>>>(x, w1f, b1, W2, b2, start,
                                              pooledPart, mPart, swPart, nrows);
  ap_final<<<bseg, 64, 0, stream>>>(pooledPart, mPart, swPart, start, out, nrows);
}

// Round 11
// 231.291 us; speedup vs baseline: 2.3455x; 1.4538x over previous
//
#include <hip/hip_runtime.h>
#include <math.h>

typedef float f32x4 __attribute__((ext_vector_type(4)));
typedef __attribute__((ext_vector_type(8))) _Float16 f16x8;

#define DD 256
#define DH 128
#define NSPLIT 4
#define TROWS 64  // rows per block tile

// ---------------------------------------------------------------------------
// K0: W1 (256x128 fp32) -> f16 MFMA B-fragment order.
// w1f[((kt*8+nt)*64+l)*8+j] = f16(W1[kt*32+(l>>4)*8+j][nt*16+(l&15)])
// ---------------------------------------------------------------------------
__global__ void ap_prep(const float* __restrict__ W1, _Float16* __restrict__ w1f) {
  int t = blockIdx.x * blockDim.x + threadIdx.x;  // 0..4095
  if (t >= 64 * 64) return;
  int l = t & 63;
  int tile = t >> 6;  // kt*8 + nt
  int kt = tile >> 3, nt = tile & 7;
  int kbase = kt * 32 + (l >> 4) * 8;
  int col = nt * 16 + (l & 15);
#pragma unroll
  for (int j = 0; j < 8; ++j) {
    w1f[t * 8 + j] = (_Float16)W1[(kbase + j) * DH + col];
  }
}

// ---------------------------------------------------------------------------
// K1: segment boundaries (batch sorted). start[b] = first i with batch[i]>=b
// ---------------------------------------------------------------------------
__global__ void ap_bounds(const int* __restrict__ batch, int* __restrict__ start,
                          int nrows, int bseg) {
  int i = blockIdx.x * blockDim.x + threadIdx.x;
  if (i >= nrows) return;
  int c = batch[i];
  int p = (i == 0) ? -1 : batch[i - 1];
  for (int b = p + 1; b <= c; ++b) start[b] = i;
  if (i == nrows - 1) {
    for (int b = c + 1; b <= bseg; ++b) start[b] = nrows;
  }
}

// ---------------------------------------------------------------------------
// K2: fused, block = (segment, piece). ALL x loads coalesced: wave (g,hw)
// loads its 8 rows as whole contiguous 1KB rows (lane l = chunk l) into
// xcol[8] registers; pooling is lane-local (accp += w_i*xcol[i], ONE f32x4);
// the MFMA A-fragments come from a 64KB XOR-swizzled LDS copy of the tile.
// B fragments stream from L2 (64KB, hot). Per-piece online max (shift
// cancels except the 1e-8 term, ~1e-13 rel). 3 barriers/tile.
// Deterministic: fixed-order reductions, no fp atomics.
// ---------------------------------------------------------------------------
__global__ __launch_bounds__(512)
void ap_fused(const float* __restrict__ x, const _Float16* __restrict__ w1f,
              const float* __restrict__ b1, const float* __restrict__ W2,
              const float* __restrict__ b2, const int* __restrict__ start,
              float* __restrict__ pooledPart, float* __restrict__ mPart,
              float* __restrict__ swPart, int nrows) {
  __shared__ __align__(16) float xs[TROWS * 256];  // 64 KB, swizzled tile
  __shared__ float praw[2][TROWS];                 // per-half epilogue partials
  __shared__ __align__(16) float pooled[8][256];   // per-wave pooled chunks
  __shared__ float swArr[8];

  const int tid = threadIdx.x;
  const int wv = tid >> 6;   // 0..7
  const int g = wv >> 1;     // 16-row group 0..3
  const int hw = wv & 1;     // half: rows hw*8.., nt hw*4..
  const int l = tid & 63;
  const int l15 = l & 15, lhi = l >> 4;

  const int bi = blockIdx.x;
  const int b = bi >> 2;
  const int q = bi & (NSPLIT - 1);
  const int s0 = start[b], e0 = start[b + 1];
  const int cnt = e0 - s0;
  const int L = (cnt + NSPLIT - 1) >> 2;
  const int s = s0 + q * L;
  int pe = s + L;
  if (pe > e0) pe = e0;
  const int e = pe;

  float b1f[4], w2f[4];
#pragma unroll
  for (int nt = 0; nt < 4; ++nt) {
    const int idx = (hw * 4 + nt) * 16 + l15;
    b1f[nt] = b1[idx];
    w2f[nt] = W2[idx];
  }
  const float bb = *b2;
  const float NI = -__builtin_inff();

  f32x4 accp = {0.f, 0.f, 0.f, 0.f};  // lane-local pooled chunk (cols l*4..)
  float m = NI;
  float swv = 0.f;

  for (int t0 = s; t0 < e; t0 += TROWS) {
    // ---- coalesced load: wave's 8 rows, lane l = chunk l (1KB/instr) ----
    f32x4 xcol[8];
#pragma unroll
    for (int i = 0; i < 8; ++i) {
      const int R = g * 16 + hw * 8 + i;
      int grow = t0 + R;
      if (grow > e - 1) grow = e - 1;
      xcol[i] = *(const f32x4*)(x + (size_t)grow * DD + l * 4);
    }
    __syncthreads();  // b1: everyone done reading xs/praw of previous tile

    // ---- ds_write swizzled: LDS chunk = R*64 + (l ^ (R&7)); R&7 == i ----
#pragma unroll
    for (int i = 0; i < 8; ++i) {
      const int R = g * 16 + hw * 8 + i;
      *(f32x4*)(xs + (size_t)(R * 64 + (l ^ i)) * 4) = xcol[i];
    }
    __syncthreads();  // b2: xs tile ready

    // ---- MFMA: A from LDS (swizzled read), B from L2; wave's 4 nt ----
    f32x4 acc[4];
#pragma unroll
    for (int nt = 0; nt < 4; ++nt) acc[nt] = f32x4{0.f, 0.f, 0.f, 0.f};
    const int Rr = g * 16 + l15;
    const int sx = l15 & 7;
#pragma unroll
    for (int kt = 0; kt < 8; ++kt) {
      const int c = kt * 8 + lhi * 2;
      const f32x4 a0 = *(const f32x4*)(xs + (size_t)(Rr * 64 + (c ^ sx)) * 4);
      const f32x4 a1 = *(const f32x4*)(xs + (size_t)(Rr * 64 + ((c + 1) ^ sx)) * 4);
      f16x8 ah, al;
#pragma unroll
      for (int j = 0; j < 8; ++j) {
        const float f = (j < 4) ? a0[j] : a1[j - 4];
        const _Float16 h = (_Float16)f;
        ah[j] = h;
        al[j] = (_Float16)(f - (float)h);
      }
#pragma unroll
      for (int nt = 0; nt < 4; ++nt) {
        const f16x8 Bh =
            *((const f16x8*)w1f + (size_t)(kt * 8 + hw * 4 + nt) * 64 + l);
        acc[nt] = __builtin_amdgcn_mfma_f32_16x16x32_f16(ah, Bh, acc[nt], 0, 0, 0);
        acc[nt] = __builtin_amdgcn_mfma_f32_16x16x32_f16(al, Bh, acc[nt], 0, 0, 0);
      }
    }

    // ---- epilogue: relu+b1, dot W2 (this wave's 64 features), reduce ----
    float pr[4];
#pragma unroll
    for (int r = 0; r < 4; ++r) pr[r] = 0.f;
#pragma unroll
    for (int nt = 0; nt < 4; ++nt) {
#pragma unroll
      for (int r = 0; r < 4; ++r)
        pr[r] += fmaxf(acc[nt][r] + b1f[nt], 0.f) * w2f[nt];
    }
#pragma unroll
    for (int mm = 1; mm < 16; mm <<= 1) {
#pragma unroll
      for (int r = 0; r < 4; ++r) pr[r] += __shfl_xor(pr[r], mm, 64);
    }
    if (l15 == 0) {
#pragma unroll
      for (int r = 0; r < 4; ++r) praw[hw][g * 16 + lhi * 4 + r] = pr[r];
    }
    __syncthreads();  // b3: praw ready

    // ---- block-uniform online softmax over the 64 tile rows ----
    const float rl = (t0 + l < e) ? (praw[0][l] + praw[1][l] + bb) : NI;
    float tv = rl;
#pragma unroll
    for (int mm = 1; mm < 64; mm <<= 1) tv = fmaxf(tv, __shfl_xor(tv, mm, 64));
    const float nm = fmaxf(m, tv);       // row t0 valid -> finite
    const float factor = expf(m - nm);   // first tile: exp(-inf) = 0
    m = nm;
    accp *= factor;
    swv *= factor;

    // ---- lane-local pooling over this wave's 8 rows (broadcast praw) ----
#pragma unroll
    for (int i = 0; i < 8; ++i) {
      const int R = g * 16 + hw * 8 + i;
      const float rv = (t0 + R < e) ? (praw[0][R] + praw[1][R] + bb) : NI;
      const float wi = expf(rv - m);     // invalid row -> 0
      swv += wi;
      accp += wi * xcol[i];
    }
  }

  // ---- combine 8 wave partials (m is block-uniform), write piece ----
  *(f32x4*)&pooled[wv][l * 4] = accp;
  if (l == 0) swArr[wv] = swv;
  __syncthreads();
  if (tid < 64) {
    float sum_w = 0.f;
#pragma unroll
    for (int p = 0; p < 8; ++p) sum_w += swArr[p];
    f32x4 v = (((f32x4*)pooled[0])[tid] + ((f32x4*)pooled[1])[tid]) +
              (((f32x4*)pooled[2])[tid] + ((f32x4*)pooled[3])[tid]);
    f32x4 w = (((f32x4*)pooled[4])[tid] + ((f32x4*)pooled[5])[tid]) +
              (((f32x4*)pooled[6])[tid] + ((f32x4*)pooled[7])[tid]);
    *(f32x4*)(pooledPart + (size_t)bi * DD + tid * 4) = v + w;
    if (tid == 0) { mPart[bi] = m; swPart[bi] = sum_w; }
  }
}

// ---------------------------------------------------------------------------
// K3: merge the NSPLIT piece partials per segment (fixed order), scale, write.
// ---------------------------------------------------------------------------
__global__ __launch_bounds__(64)
void ap_final(const float* __restrict__ pooledPart, const float* __restrict__ mPart,
              const float* __restrict__ swPart, const int* __restrict__ start,
              float* __restrict__ out, int nrows) {
  const int b = blockIdx.x;
  const int tid = threadIdx.x;
  const float NI = -__builtin_inff();
  float mq[NSPLIT];
#pragma unroll
  for (int qv = 0; qv < NSPLIT; ++qv) mq[qv] = mPart[b * NSPLIT + qv];
  float m_f = NI;
#pragma unroll
  for (int qv = 0; qv < NSPLIT; ++qv) m_f = fmaxf(m_f, mq[qv]);
  float fac[NSPLIT];
  float sum_w = 0.f;
#pragma unroll
  for (int qv = 0; qv < NSPLIT; ++qv) {
    fac[qv] = (mq[qv] == NI) ? 0.f : expf(mq[qv] - m_f);
    sum_w += swPart[b * NSPLIT + qv] * fac[qv];
  }
  const int cnt = start[b + 1] - start[b];
  const float cntf = (float)(cnt > 0 ? cnt : 1);
  const float scale = 1.0f / (((sum_w / cntf) * (float)nrows + 1e-8f) * cntf);
  f32x4 r = f32x4{0.f, 0.f, 0.f, 0.f};
#pragma unroll
  for (int qv = 0; qv < NSPLIT; ++qv) {
    r += ((const f32x4*)(pooledPart + (size_t)(b * NSPLIT + qv) * DD))[tid] * fac[qv];
  }
  r *= scale;
  *(f32x4*)(out + (size_t)b * DD + tid * 4) = r;
}

extern "C" void kernel_launch(void* const* d_in, const int* in_sizes, int n_in,
                              void* d_out, int out_size, void* d_ws, size_t ws_size,
                              hipStream_t stream) {
  const float* x     = (const float*)d_in[0];
  const int*   batch = (const int*)d_in[1];
  const float* W1    = (const float*)d_in[2];
  const float* b1    = (const float*)d_in[3];
  const float* W2    = (const float*)d_in[4];
  const float* b2    = (const float*)d_in[5];
  float* out = (float*)d_out;

  const int nrows = in_sizes[1];
  const int bseg = out_size / DD;

  // workspace layout (16B-aligned)
  float* pooledPart = (float*)d_ws;                        // bseg*4*256 f32
  float* mPart  = pooledPart + (size_t)bseg * NSPLIT * DD; // bseg*4
  float* swPart = mPart + bseg * NSPLIT;                   // bseg*4
  _Float16* w1f = (_Float16*)(swPart + bseg * NSPLIT);     // 64 KB
  int* start = (int*)(w1f + 64 * 64 * 8);                  // bseg+1

  ap_prep<<<16, 256, 0, stream>>>(W1, w1f);
  ap_bounds<<<(nrows + 255) / 256, 256, 0, stream>>>(batch, start, nrows, bseg);
  ap_fused<<<bseg * NSPLIT, 512, 0, stream>>>(x, w1f, b1, W2, b2, start,
                                              pooledPart, mPart, swPart, nrows);
  ap_final<<<bseg, 64, 0, stream>>>(pooledPart, mPart, swPart, start, out, nrows);
}

// Round 12
// 223.004 us; speedup vs baseline: 2.4326x; 1.0372x over previous
//
#include <hip/hip_runtime.h>
#include <math.h>

typedef float f32x4 __attribute__((ext_vector_type(4)));
typedef __attribute__((ext_vector_type(8))) _Float16 f16x8;

#define DD 256
#define DH 128
#define NSPLIT 4
#define TROWS 64  // rows per block tile

// ---------------------------------------------------------------------------
// K0 (merged): blocks 0..15: W1 -> f16 MFMA B-fragment order
//   w1f[((kt*8+nt)*64+l)*8+j] = f16(W1[kt*32+(l>>4)*8+j][nt*16+(l&15)])
// blocks 16..: segment boundaries (batch sorted).
// ---------------------------------------------------------------------------
__global__ void ap_setup(const float* __restrict__ W1, _Float16* __restrict__ w1f,
                         const int* __restrict__ batch, int* __restrict__ start,
                         int nrows, int bseg) {
  const int bid = blockIdx.x;
  if (bid < 16) {
    int t = bid * 256 + threadIdx.x;  // 0..4095
    int l = t & 63;
    int tile = t >> 6;  // kt*8 + nt
    int kt = tile >> 3, nt = tile & 7;
    int kbase = kt * 32 + (l >> 4) * 8;
    int col = nt * 16 + (l & 15);
#pragma unroll
    for (int j = 0; j < 8; ++j) {
      w1f[t * 8 + j] = (_Float16)W1[(kbase + j) * DH + col];
    }
  } else {
    int i = (bid - 16) * 256 + threadIdx.x;
    if (i >= nrows) return;
    int c = batch[i];
    int p = (i == 0) ? -1 : batch[i - 1];
    for (int b = p + 1; b <= c; ++b) start[b] = i;
    if (i == nrows - 1) {
      for (int b = c + 1; b <= bseg; ++b) start[b] = nrows;
    }
  }
}

// ---------------------------------------------------------------------------
// K2: fused, block = (segment, piece). All x loads coalesced (lane=chunk,
// 1KB/instr). Async-stage split (T14): next tile's x loads issue right after
// the ds_write barrier, hiding HBM latency under MFMA+epilogue+pooling;
// pooling re-reads the swizzled LDS tile (conflict-free permutation) instead
// of keeping xcol live. Per-piece online max (shift cancels except the 1e-8
// term, ~1e-13 rel). pooled partials alias xs after the loop.
// Deterministic: fixed-order reductions, no fp atomics.
// ---------------------------------------------------------------------------
__global__ __launch_bounds__(512)
void ap_fused(const float* __restrict__ x, const _Float16* __restrict__ w1f,
              const float* __restrict__ b1, const float* __restrict__ W2,
              const float* __restrict__ b2, const int* __restrict__ start,
              float* __restrict__ pooledPart, float* __restrict__ mPart,
              float* __restrict__ swPart, int nrows) {
  __shared__ __align__(16) float xs[TROWS * 256];  // 64 KB swizzled tile (+pooled alias)
  __shared__ float praw[2][TROWS];                 // per-half epilogue partials
  __shared__ float swArr[8];

  const int tid = threadIdx.x;
  const int wv = tid >> 6;   // 0..7
  const int g = wv >> 1;     // 16-row group 0..3
  const int hw = wv & 1;     // half: rows hw*8.., nt hw*4..
  const int l = tid & 63;
  const int l15 = l & 15, lhi = l >> 4;

  const int bi = blockIdx.x;
  const int b = bi >> 2;
  const int q = bi & (NSPLIT - 1);
  const int s0 = start[b], e0 = start[b + 1];
  const int cnt = e0 - s0;
  const int L = (cnt + NSPLIT - 1) >> 2;
  const int s = s0 + q * L;
  int pe = s + L;
  if (pe > e0) pe = e0;
  const int e = pe;
  const int ce = (e > 0) ? (e - 1) : 0;  // safe clamp row

  float b1f[4], w2f[4];
#pragma unroll
  for (int nt = 0; nt < 4; ++nt) {
    const int idx = (hw * 4 + nt) * 16 + l15;
    b1f[nt] = b1[idx];
    w2f[nt] = W2[idx];
  }
  const float bb = *b2;
  const float NI = -__builtin_inff();

  f32x4 accp = {0.f, 0.f, 0.f, 0.f};  // lane-local pooled chunk (cols l*4..)
  float m = NI;
  float swv = 0.f;

  // prologue: load first tile's rows (coalesced: lane l = chunk l)
  f32x4 xcol[8];
#pragma unroll
  for (int i = 0; i < 8; ++i) {
    const int R = g * 16 + hw * 8 + i;
    int grow = s + R;
    if (grow > ce) grow = ce;
    if (grow < 0) grow = 0;
    xcol[i] = *(const f32x4*)(x + (size_t)grow * DD + l * 4);
  }

  for (int t0 = s; t0 < e; t0 += TROWS) {
    __syncthreads();  // b1: previous tile's xs reads (MFMA + pooling) done

    // ---- ds_write swizzled: LDS chunk = R*64 + (l ^ (R&7)) ----
#pragma unroll
    for (int i = 0; i < 8; ++i) {
      const int R = g * 16 + hw * 8 + i;
      *(f32x4*)(xs + (size_t)(R * 64 + (l ^ i)) * 4) = xcol[i];
    }
    __syncthreads();  // b2: xs tile ready

    // ---- prefetch next tile into xcol (latency hides under compute) ----
    if (t0 + TROWS < e) {
#pragma unroll
      for (int i = 0; i < 8; ++i) {
        const int R = g * 16 + hw * 8 + i;
        int grow = t0 + TROWS + R;
        if (grow > ce) grow = ce;
        xcol[i] = *(const f32x4*)(x + (size_t)grow * DD + l * 4);
      }
    }

    // ---- MFMA: A from LDS (swizzled read), B from L2; wave's 4 nt ----
    f32x4 acc[4];
#pragma unroll
    for (int nt = 0; nt < 4; ++nt) acc[nt] = f32x4{0.f, 0.f, 0.f, 0.f};
    const int Rr = g * 16 + l15;
    const int sx = l15 & 7;
#pragma unroll
    for (int kt = 0; kt < 8; ++kt) {
      const int c = kt * 8 + lhi * 2;
      const f32x4 a0 = *(const f32x4*)(xs + (size_t)(Rr * 64 + (c ^ sx)) * 4);
      const f32x4 a1 = *(const f32x4*)(xs + (size_t)(Rr * 64 + ((c + 1) ^ sx)) * 4);
      f16x8 ah, al;
#pragma unroll
      for (int j = 0; j < 8; ++j) {
        const float f = (j < 4) ? a0[j] : a1[j - 4];
        const _Float16 h = (_Float16)f;
        ah[j] = h;
        al[j] = (_Float16)(f - (float)h);
      }
#pragma unroll
      for (int nt = 0; nt < 4; ++nt) {
        const f16x8 Bh =
            *((const f16x8*)w1f + (size_t)(kt * 8 + hw * 4 + nt) * 64 + l);
        acc[nt] = __builtin_amdgcn_mfma_f32_16x16x32_f16(ah, Bh, acc[nt], 0, 0, 0);
        acc[nt] = __builtin_amdgcn_mfma_f32_16x16x32_f16(al, Bh, acc[nt], 0, 0, 0);
      }
    }

    // ---- epilogue: relu+b1, dot W2 (this wave's 64 features), reduce ----
    float pr[4];
#pragma unroll
    for (int r = 0; r < 4; ++r) pr[r] = 0.f;
#pragma unroll
    for (int nt = 0; nt < 4; ++nt) {
#pragma unroll
      for (int r = 0; r < 4; ++r)
        pr[r] += fmaxf(acc[nt][r] + b1f[nt], 0.f) * w2f[nt];
    }
#pragma unroll
    for (int mm = 1; mm < 16; mm <<= 1) {
#pragma unroll
      for (int r = 0; r < 4; ++r) pr[r] += __shfl_xor(pr[r], mm, 64);
    }
    if (l15 == 0) {
#pragma unroll
      for (int r = 0; r < 4; ++r) praw[hw][g * 16 + lhi * 4 + r] = pr[r];
    }
    __syncthreads();  // b3: praw ready

    // ---- block-uniform online softmax over the 64 tile rows ----
    const float tot = (t0 + l < e) ? (praw[0][l] + praw[1][l] + bb) : NI;
    float tv = tot;
#pragma unroll
    for (int mm = 1; mm < 64; mm <<= 1) tv = fmaxf(tv, __shfl_xor(tv, mm, 64));
    const float nm = fmaxf(m, tv);       // row t0 valid -> finite
    const float factor = expf(m - nm);   // first tile: exp(-inf) = 0
    m = nm;
    accp *= factor;
    swv *= factor;

    // ---- pooling: re-read this wave's 8 rows from xs (swizzled) ----
#pragma unroll
    for (int i = 0; i < 8; ++i) {
      const int R = g * 16 + hw * 8 + i;
      const float wi = expf(__shfl(tot, R, 64) - m);  // invalid row -> 0
      const f32x4 xv = *(const f32x4*)(xs + (size_t)(R * 64 + (l ^ i)) * 4);
      swv += wi;
      accp += wi * xv;
    }
  }

  // ---- combine 8 wave partials (m is block-uniform), write piece ----
  __syncthreads();                      // all xs reads done; alias as pooled
  ((f32x4*)xs)[wv * 64 + l] = accp;     // pooled[wv][chunk l]
  if (l == 0) swArr[wv] = swv;
  __syncthreads();
  if (tid < 64) {
    float sum_w = 0.f;
#pragma unroll
    for (int p = 0; p < 8; ++p) sum_w += swArr[p];
    const f32x4* pw = (const f32x4*)xs;
    f32x4 v = ((pw[0 * 64 + tid] + pw[1 * 64 + tid]) +
               (pw[2 * 64 + tid] + pw[3 * 64 + tid]));
    f32x4 w = ((pw[4 * 64 + tid] + pw[5 * 64 + tid]) +
               (pw[6 * 64 + tid] + pw[7 * 64 + tid]));
    *(f32x4*)(pooledPart + (size_t)bi * DD + tid * 4) = v + w;
    if (tid == 0) { mPart[bi] = m; swPart[bi] = sum_w; }
  }
}

// ---------------------------------------------------------------------------
// K3: merge the NSPLIT piece partials per segment (fixed order), scale, write.
// ---------------------------------------------------------------------------
__global__ __launch_bounds__(64)
void ap_final(const float* __restrict__ pooledPart, const float* __restrict__ mPart,
              const float* __restrict__ swPart, const int* __restrict__ start,
              float* __restrict__ out, int nrows) {
  const int b = blockIdx.x;
  const int tid = threadIdx.x;
  const float NI = -__builtin_inff();
  float mq[NSPLIT];
#pragma unroll
  for (int qv = 0; qv < NSPLIT; ++qv) mq[qv] = mPart[b * NSPLIT + qv];
  float m_f = NI;
#pragma unroll
  for (int qv = 0; qv < NSPLIT; ++qv) m_f = fmaxf(m_f, mq[qv]);
  float fac[NSPLIT];
  float sum_w = 0.f;
#pragma unroll
  for (int qv = 0; qv < NSPLIT; ++qv) {
    fac[qv] = (mq[qv] == NI) ? 0.f : expf(mq[qv] - m_f);
    sum_w += swPart[b * NSPLIT + qv] * fac[qv];
  }
  const int cnt = start[b + 1] - start[b];
  const float cntf = (float)(cnt > 0 ? cnt : 1);
  const float scale = 1.0f / (((sum_w / cntf) * (float)nrows + 1e-8f) * cntf);
  f32x4 r = f32x4{0.f, 0.f, 0.f, 0.f};
#pragma unroll
  for (int qv = 0; qv < NSPLIT; ++qv) {
    r += ((const f32x4*)(pooledPart + (size_t)(b * NSPLIT + qv) * DD))[tid] * fac[qv];
  }
  r *= scale;
  *(f32x4*)(out + (size_t)b * DD + tid * 4) = r;
}

extern "C" void kernel_launch(void* const* d_in, const int* in_sizes, int n_in,
                              void* d_out, int out_size, void* d_ws, size_t ws_size,
                              hipStream_t stream) {
  const float* x     = (const float*)d_in[0];
  const int*   batch = (const int*)d_in[1];
  const float* W1    = (const float*)d_in[2];
  const float* b1    = (const float*)d_in[3];
  const float* W2    = (const float*)d_in[4];
  const float* b2    = (const float*)d_in[5];
  float* out = (float*)d_out;

  const int nrows = in_sizes[1];
  const int bseg = out_size / DD;

  // workspace layout (16B-aligned)
  float* pooledPart = (float*)d_ws;                        // bseg*4*256 f32
  float* mPart  = pooledPart + (size_t)bseg * NSPLIT * DD; // bseg*4
  float* swPart = mPart + bseg * NSPLIT;                   // bseg*4
  _Float16* w1f = (_Float16*)(swPart + bseg * NSPLIT);     // 64 KB
  int* start = (int*)(w1f + 64 * 64 * 8);                  // bseg+1

  ap_setup<<<16 + (nrows + 255) / 256, 256, 0, stream>>>(W1, w1f, batch, start,
                                                         nrows, bseg);
  ap_fused<<<bseg * NSPLIT, 512, 0, stream>>>(x, w1f, b1, W2, b2, start,
                                              pooledPart, mPart, swPart, nrows);
  ap_final<<<bseg, 64, 0, stream>>>(pooledPart, mPart, swPart, start, out, nrows);
}

// Round 13
// 191.973 us; speedup vs baseline: 2.8258x; 1.1616x over previous
//
#include <hip/hip_runtime.h>
#include <math.h>

typedef float f32x4 __attribute__((ext_vector_type(4)));
typedef __attribute__((ext_vector_type(8))) _Float16 f16x8;

#define DD 256
#define DH 128
#define NSPLIT 2
#define TROWS 64  // rows per block tile

// ---------------------------------------------------------------------------
// K0 (merged): blocks 0..15: W1 -> f16 MFMA B-fragment order
//   w1f[((kt*8+nt)*64+l)*8+j] = f16(W1[kt*32+(l>>4)*8+j][nt*16+(l&15)])
// blocks 16..: segment boundaries (batch sorted).
// ---------------------------------------------------------------------------
__global__ void ap_setup(const float* __restrict__ W1, _Float16* __restrict__ w1f,
                         const int* __restrict__ batch, int* __restrict__ start,
                         int nrows, int bseg) {
  const int bid = blockIdx.x;
  if (bid < 16) {
    int t = bid * 256 + threadIdx.x;  // 0..4095
    int l = t & 63;
    int tile = t >> 6;  // kt*8 + nt
    int kt = tile >> 3, nt = tile & 7;
    int kbase = kt * 32 + (l >> 4) * 8;
    int col = nt * 16 + (l & 15);
#pragma unroll
    for (int j = 0; j < 8; ++j) {
      w1f[t * 8 + j] = (_Float16)W1[(kbase + j) * DH + col];
    }
  } else {
    int i = (bid - 16) * 256 + threadIdx.x;
    if (i >= nrows) return;
    int c = batch[i];
    int p = (i == 0) ? -1 : batch[i - 1];
    for (int b = p + 1; b <= c; ++b) start[b] = i;
    if (i == nrows - 1) {
      for (int b = c + 1; b <= bseg; ++b) start[b] = nrows;
    }
  }
}

// ---------------------------------------------------------------------------
// K2: fused, block = (segment, piece). x loads coalesced (lane=chunk,
// 1KB/instr) with async prefetch; x tile XOR-swizzled in LDS; B fragments
// staged ONCE per block into LDS (64 KB) -> kt-loop has ZERO VMEM
// dependency (kills the 2.1 GB L2 B-stream that capped rounds 7-12).
// LDS = 64(xs) + 64(sB) + 1 KB -> 1 block/CU, 8 waves. Per-piece online max
// (shift cancels except the 1e-8 term, ~1e-13 rel). pooled aliases xs after
// the loop. Deterministic: fixed-order reductions, no fp atomics.
// ---------------------------------------------------------------------------
__global__ __launch_bounds__(512)
void ap_fused(const float* __restrict__ x, const _Float16* __restrict__ w1f,
              const float* __restrict__ b1, const float* __restrict__ W2,
              const float* __restrict__ b2, const int* __restrict__ start,
              float* __restrict__ pooledPart, float* __restrict__ mPart,
              float* __restrict__ swPart, int nrows) {
  __shared__ __align__(16) float xs[TROWS * 256];     // 64 KB swizzled x tile
  __shared__ __align__(16) _Float16 sB[64 * 64 * 8];  // 64 KB B fragments
  __shared__ float praw[2][TROWS];
  __shared__ float swArr[8];

  const int tid = threadIdx.x;
  const int wv = tid >> 6;   // 0..7
  const int g = wv >> 1;     // 16-row group 0..3
  const int hw = wv & 1;     // half: nt hw*4..
  const int l = tid & 63;
  const int l15 = l & 15, lhi = l >> 4;

  const int bi = blockIdx.x;
  const int b = bi >> 1;
  const int q = bi & (NSPLIT - 1);
  const int s0 = start[b], e0 = start[b + 1];
  const int cnt = e0 - s0;
  const int L = (cnt + NSPLIT - 1) >> 1;
  const int s = s0 + q * L;
  int pe = s + L;
  if (pe > e0) pe = e0;
  const int e = pe;
  const int ce = (e > 0) ? (e - 1) : 0;  // safe clamp row

  // stage B fragments into LDS (once per block): 4096 x 16B chunks
  {
    const f32x4* src = (const f32x4*)w1f;
    f32x4* dst = (f32x4*)sB;
#pragma unroll
    for (int it = 0; it < 8; ++it) dst[it * 512 + tid] = src[it * 512 + tid];
  }

  float b1f[4], w2f[4];
#pragma unroll
  for (int nt = 0; nt < 4; ++nt) {
    const int idx = (hw * 4 + nt) * 16 + l15;
    b1f[nt] = b1[idx];
    w2f[nt] = W2[idx];
  }
  const float bb = *b2;
  const float NI = -__builtin_inff();

  f32x4 accp = {0.f, 0.f, 0.f, 0.f};  // lane-local pooled chunk (cols l*4..)
  float m = NI;
  float swv = 0.f;

  // prologue: load first tile's rows (coalesced: lane l = chunk l)
  f32x4 xcol[8];
#pragma unroll
  for (int i = 0; i < 8; ++i) {
    const int R = g * 16 + hw * 8 + i;
    int grow = s + R;
    if (grow > ce) grow = ce;
    if (grow < 0) grow = 0;
    xcol[i] = *(const f32x4*)(x + (size_t)grow * DD + l * 4);
  }
  __syncthreads();  // sB staged (covers prologue too)

  for (int t0 = s; t0 < e; t0 += TROWS) {
    // ---- ds_write swizzled: LDS chunk = R*64 + (l ^ (R&7)) ----
#pragma unroll
    for (int i = 0; i < 8; ++i) {
      const int R = g * 16 + hw * 8 + i;
      *(f32x4*)(xs + (size_t)(R * 64 + (l ^ i)) * 4) = xcol[i];
    }
    __syncthreads();  // b2: xs tile ready

    // ---- prefetch next tile into xcol (latency hides under compute) ----
    if (t0 + TROWS < e) {
#pragma unroll
      for (int i = 0; i < 8; ++i) {
        const int R = g * 16 + hw * 8 + i;
        int grow = t0 + TROWS + R;
        if (grow > ce) grow = ce;
        xcol[i] = *(const f32x4*)(x + (size_t)grow * DD + l * 4);
      }
    }

    // ---- MFMA: A from LDS (swizzled read), B from LDS; wave's 4 nt ----
    f32x4 acc[4];
#pragma unroll
    for (int nt = 0; nt < 4; ++nt) acc[nt] = f32x4{0.f, 0.f, 0.f, 0.f};
    const int Rr = g * 16 + l15;
    const int sx = l15 & 7;
#pragma unroll
    for (int kt = 0; kt < 8; ++kt) {
      const int c = kt * 8 + lhi * 2;
      const f32x4 a0 = *(const f32x4*)(xs + (size_t)(Rr * 64 + (c ^ sx)) * 4);
      const f32x4 a1 = *(const f32x4*)(xs + (size_t)(Rr * 64 + ((c + 1) ^ sx)) * 4);
      f16x8 ah, al;
#pragma unroll
      for (int j = 0; j < 8; ++j) {
        const float f = (j < 4) ? a0[j] : a1[j - 4];
        const _Float16 h = (_Float16)f;
        ah[j] = h;
        al[j] = (_Float16)(f - (float)h);
      }
#pragma unroll
      for (int nt = 0; nt < 4; ++nt) {
        const f16x8 Bh =
            *((const f16x8*)sB + (size_t)(kt * 8 + hw * 4 + nt) * 64 + l);
        acc[nt] = __builtin_amdgcn_mfma_f32_16x16x32_f16(ah, Bh, acc[nt], 0, 0, 0);
        acc[nt] = __builtin_amdgcn_mfma_f32_16x16x32_f16(al, Bh, acc[nt], 0, 0, 0);
      }
    }

    // ---- epilogue: relu+b1, dot W2 (this wave's 64 features), reduce ----
    float pr[4];
#pragma unroll
    for (int r = 0; r < 4; ++r) pr[r] = 0.f;
#pragma unroll
    for (int nt = 0; nt < 4; ++nt) {
#pragma unroll
      for (int r = 0; r < 4; ++r)
        pr[r] += fmaxf(acc[nt][r] + b1f[nt], 0.f) * w2f[nt];
    }
#pragma unroll
    for (int mm = 1; mm < 16; mm <<= 1) {
#pragma unroll
      for (int r = 0; r < 4; ++r) pr[r] += __shfl_xor(pr[r], mm, 64);
    }
    if (l15 == 0) {
#pragma unroll
      for (int r = 0; r < 4; ++r) praw[hw][g * 16 + lhi * 4 + r] = pr[r];
    }
    __syncthreads();  // b3: praw ready

    // ---- block-uniform online softmax over the 64 tile rows ----
    const float tot = (t0 + l < e) ? (praw[0][l] + praw[1][l] + bb) : NI;
    float tv = tot;
#pragma unroll
    for (int mm = 1; mm < 64; mm <<= 1) tv = fmaxf(tv, __shfl_xor(tv, mm, 64));
    const float nm = fmaxf(m, tv);       // row t0 valid -> finite
    const float factor = expf(m - nm);   // first tile: exp(-inf) = 0
    m = nm;
    accp *= factor;
    swv *= factor;

    // ---- pooling: re-read this wave's 8 rows from xs (swizzled) ----
#pragma unroll
    for (int i = 0; i < 8; ++i) {
      const int R = g * 16 + hw * 8 + i;
      const float wi = expf(__shfl(tot, R, 64) - m);  // invalid row -> 0
      const f32x4 xv = *(const f32x4*)(xs + (size_t)(R * 64 + (l ^ i)) * 4);
      swv += wi;
      accp += wi * xv;
    }
    __syncthreads();  // b1: xs reads done; next ds_write may overwrite
  }

  // ---- combine 8 wave partials (m is block-uniform), write piece ----
  ((f32x4*)xs)[wv * 64 + l] = accp;     // pooled[wv][chunk l] (alias xs)
  if (l == 0) swArr[wv] = swv;
  __syncthreads();
  if (tid < 64) {
    float sum_w = 0.f;
#pragma unroll
    for (int p = 0; p < 8; ++p) sum_w += swArr[p];
    const f32x4* pw = (const f32x4*)xs;
    f32x4 v = ((pw[0 * 64 + tid] + pw[1 * 64 + tid]) +
               (pw[2 * 64 + tid] + pw[3 * 64 + tid]));
    f32x4 w = ((pw[4 * 64 + tid] + pw[5 * 64 + tid]) +
               (pw[6 * 64 + tid] + pw[7 * 64 + tid]));
    *(f32x4*)(pooledPart + (size_t)bi * DD + tid * 4) = v + w;
    if (tid == 0) { mPart[bi] = m; swPart[bi] = sum_w; }
  }
}

// ---------------------------------------------------------------------------
// K3: merge the NSPLIT piece partials per segment (fixed order), scale, write.
// ---------------------------------------------------------------------------
__global__ __launch_bounds__(64)
void ap_final(const float* __restrict__ pooledPart, const float* __restrict__ mPart,
              const float* __restrict__ swPart, const int* __restrict__ start,
              float* __restrict__ out, int nrows) {
  const int b = blockIdx.x;
  const int tid = threadIdx.x;
  const float NI = -__builtin_inff();
  float mq[NSPLIT];
#pragma unroll
  for (int qv = 0; qv < NSPLIT; ++qv) mq[qv] = mPart[b * NSPLIT + qv];
  float m_f = NI;
#pragma unroll
  for (int qv = 0; qv < NSPLIT; ++qv) m_f = fmaxf(m_f, mq[qv]);
  float fac[NSPLIT];
  float sum_w = 0.f;
#pragma unroll
  for (int qv = 0; qv < NSPLIT; ++qv) {
    fac[qv] = (mq[qv] == NI) ? 0.f : expf(mq[qv] - m_f);
    sum_w += swPart[b * NSPLIT + qv] * fac[qv];
  }
  const int cnt = start[b + 1] - start[b];
  const float cntf = (float)(cnt > 0 ? cnt : 1);
  const float scale = 1.0f / (((sum_w / cntf) * (float)nrows + 1e-8f) * cntf);
  f32x4 r = f32x4{0.f, 0.f, 0.f, 0.f};
#pragma unroll
  for (int qv = 0; qv < NSPLIT; ++qv) {
    r += ((const f32x4*)(pooledPart + (size_t)(b * NSPLIT + qv) * DD))[tid] * fac[qv];
  }
  r *= scale;
  *(f32x4*)(out + (size_t)b * DD + tid * 4) = r;
}

extern "C" void kernel_launch(void* const* d_in, const int* in_sizes, int n_in,
                              void* d_out, int out_size, void* d_ws, size_t ws_size,
                              hipStream_t stream) {
  const float* x     = (const float*)d_in[0];
  const int*   batch = (const int*)d_in[1];
  const float* W1    = (const float*)d_in[2];
  const float* b1    = (const float*)d_in[3];
  const float* W2    = (const float*)d_in[4];
  const float* b2    = (const float*)d_in[5];
  float* out = (float*)d_out;

  const int nrows = in_sizes[1];
  const int bseg = out_size / DD;

  // workspace layout (16B-aligned)
  float* pooledPart = (float*)d_ws;                        // bseg*2*256 f32
  float* mPart  = pooledPart + (size_t)bseg * NSPLIT * DD; // bseg*2
  float* swPart = mPart + bseg * NSPLIT;                   // bseg*2
  _Float16* w1f = (_Float16*)(swPart + bseg * NSPLIT);     // 64 KB
  int* start = (int*)(w1f + 64 * 64 * 8);                  // bseg+1

  ap_setup<<<16 + (nrows + 255) / 256, 256, 0, stream>>>(W1, w1f, batch, start,
                                                         nrows, bseg);
  ap_fused<<<bseg * NSPLIT, 512, 0, stream>>>(x, w1f, b1, W2, b2, start,
                                              pooledPart, mPart, swPart, nrows);
  ap_final<<<bseg, 64, 0, stream>>>(pooledPart, mPart, swPart, start, out, nrows);
}